// Round 7
// baseline (251.551 us; speedup 1.0000x reference)
//
#include <hip/hip_runtime.h>

#define M_ROWS 12608          // 64*197
#define K_DIM  768
#define QSZ    9682944        // 64*12*197*64 elements per q/k/v plane
#define XB_ELEMS (12800*768)  // padded bf16 X copy (lives in d_out scratch)

typedef __bf16 bf16x8 __attribute__((ext_vector_type(8)));
typedef float  f32x4  __attribute__((ext_vector_type(4)));

__device__ __forceinline__ unsigned short f2bf(float f) {
    unsigned u = __builtin_bit_cast(unsigned, f);
    u += 0x7fffu + ((u >> 16) & 1u);          // RNE, inputs are finite
    return (unsigned short)(u >> 16);
}

__device__ __forceinline__ void gll16(const unsigned short* g, unsigned short* l) {
    __builtin_amdgcn_global_load_lds(
        (const __attribute__((address_space(1))) unsigned int*)g,
        (__attribute__((address_space(3))) unsigned int*)l, 16, 0, 0);
}

// ---------------- Kernel 0: fused prep — X fp32->bf16 (padded) AND W transpose ---------
// Blocks 0..4799: x2bf to 12800 rows (pad rows zeroed). Blocks 4800..6527: wtrans.
__global__ __launch_bounds__(256) void prep_kernel(
        const float* __restrict__ X, unsigned short* __restrict__ Xb,
        const float* __restrict__ W, unsigned short* __restrict__ Wt) {
    __shared__ float tile[32][33];
    const int bid = blockIdx.x;
    if (bid < 4800) {
        size_t base = ((size_t)bid * 256 + threadIdx.x) * 8;
        if (base >= (size_t)M_ROWS * K_DIM) {   // zero pad rows 12608..12799
            *(ushort4*)(Xb + base) = (ushort4){0, 0, 0, 0};
            *(ushort4*)(Xb + base + 4) = (ushort4){0, 0, 0, 0};
            return;
        }
        float4 a = *(const float4*)(X + base);
        float4 b = *(const float4*)(X + base + 4);
        ushort4 lo, hi;
        lo.x = f2bf(a.x); lo.y = f2bf(a.y); lo.z = f2bf(a.z); lo.w = f2bf(a.w);
        hi.x = f2bf(b.x); hi.y = f2bf(b.y); hi.z = f2bf(b.z); hi.w = f2bf(b.w);
        *(ushort4*)(Xb + base) = lo;
        *(ushort4*)(Xb + base + 4) = hi;
        return;
    }
    const int b2 = bid - 4800;
    const int n0 = (b2 % 72) * 32, k0 = (b2 / 72) * 32;
    const int tx = threadIdx.x & 31, ty = threadIdx.x >> 5;
#pragma unroll
    for (int i = 0; i < 4; ++i)
        tile[ty + i * 8][tx] = W[(size_t)(k0 + ty + i * 8) * 2304 + n0 + tx];
    __syncthreads();
#pragma unroll
    for (int i = 0; i < 4; ++i)
        Wt[(size_t)(n0 + ty + i * 8) * K_DIM + k0 + tx] = f2bf(tile[tx][ty + i * 8]);
}

// ---------------- Kernel 2: QKV GEMM, 256x128 tile, 8 waves, 2-buffer ring ------------
// R3's proven per-step structure (stage-issue at top, single vmcnt(0)+barrier at
// bottom), but 2x the output per block: 900 blocks instead of 1782 halves the number
// of per-block-K-step latency hits (the measured limiter: all counters <20%, cost
// invariant to drain placement). Per wave per step: 3 gll16 + 8 ds_read_b128 +
// 16 MFMA (same as before). LDS 48 KB (A 16K + B 8K, dbuf); ~124 regs -> 2 blocks/CU
// = 16 waves/CU. Unified LDS array S: A at [0..8191], B at [8192..12287] (shorts).
__global__ __launch_bounds__(512, 4) void qkv_gemm_kernel(
        const unsigned short* __restrict__ Xb, const unsigned short* __restrict__ Wt,
        const float* __restrict__ bias, unsigned short* __restrict__ qkv) {
    __shared__ __align__(16) unsigned short S[2][12288];   // 2 x 24 KB

    // XCD-chunked bijective swizzle: 900 blocks = 8*112 + 4
    const int lin = blockIdx.x;
    const int xcd = lin & 7, ix = lin >> 3;
    const int wg = (xcd < 4) ? xcd * 113 + ix : 452 + (xcd - 4) * 112 + ix;
    const int by = wg / 18, bx = wg - by * 18;
    const int m0 = by * 256, n0 = bx * 128;

    const int t = threadIdx.x;
    const int w = t >> 6, lane = t & 63, quad = lane >> 4, l16 = lane & 15;
    const int wr = (w >> 1) * 64, wc = (w & 1) * 64;   // wave -> (M-chunk of 4, N-half)

    // staging: 24 chunks of 1 KB (64 rows x 8 k each); wave w owns chunks w*3..w*3+2.
    // chunks 0..15: A (kc=g>>2, rg=g&3); 16..23: B (kc=(g-16)>>1, rg=(g-16)&1)
    const unsigned short* sg[3];
    int so[3];
#pragma unroll
    for (int s = 0; s < 3; ++s) {
        const int g = w * 3 + s;
        if (g < 16) {
            const int kc = g >> 2, rg = g & 3;
            sg[s] = Xb + (size_t)(m0 + rg * 64 + lane) * K_DIM + kc * 8;
            so[s] = kc * 2048 + rg * 512;
        } else {
            const int g2 = g - 16, kc = g2 >> 1, rg = g2 & 1;
            sg[s] = Wt + (size_t)(n0 + rg * 64 + lane) * K_DIM + kc * 8;
            so[s] = 8192 + kc * 1024 + rg * 512;
        }
    }

    f32x4 acc[4][4];
#pragma unroll
    for (int i = 0; i < 4; ++i)
#pragma unroll
        for (int j = 0; j < 4; ++j) acc[i][j] = (f32x4){0.f, 0.f, 0.f, 0.f};

    // prologue: stage tile 0, land it
#pragma unroll
    for (int s = 0; s < 3; ++s) gll16(sg[s], &S[0][so[s]]);
    asm volatile("s_waitcnt vmcnt(0)" ::: "memory");
    __builtin_amdgcn_s_barrier();
    asm volatile("" ::: "memory");

#pragma unroll 2
    for (int kt = 0; kt < 24; ++kt) {
        const int cur = kt & 1, nxt = cur ^ 1;
        const int sk = (kt + 1 < 24 ? kt + 1 : 0) * 32;   // tail: dummy restage (dead)

        // issue next tile's staging first; the whole body below overlaps its latency
#pragma unroll
        for (int s = 0; s < 3; ++s) gll16(sg[s] + sk, &S[nxt][so[s]]);

        bf16x8 af[4], bfr[4];
#pragma unroll
        for (int i = 0; i < 4; ++i)
            af[i] = *(const bf16x8*)&S[cur][quad * 2048 + (wr + i * 16 + l16) * 8];
#pragma unroll
        for (int j = 0; j < 4; ++j)
            bfr[j] = *(const bf16x8*)&S[cur][8192 + quad * 1024 + (wc + j * 16 + l16) * 8];

#pragma unroll
        for (int i = 0; i < 4; ++i)
#pragma unroll
            for (int j = 0; j < 4; ++j)
                acc[i][j] = __builtin_amdgcn_mfma_f32_16x16x32_bf16(af[i], bfr[j], acc[i][j], 0, 0, 0);

        // drain this iter's 3 loads (latency covered by the body) + publish
        asm volatile("s_waitcnt vmcnt(0)" ::: "memory");
        __builtin_amdgcn_s_barrier();
        asm volatile("" ::: "memory");
    }

    // epilogue: bias; fold 1/8 into q; q,k,v all stored [b,h][tok][d] (coalesced)
#pragma unroll
    for (int i = 0; i < 4; ++i) {
#pragma unroll
        for (int j = 0; j < 4; ++j) {
            int gn = n0 + wc + j * 16 + l16;
            int which = gn / 768;
            int rem = gn - which * 768;
            int hh = rem >> 6, dd = rem & 63;
            float bv = bias[gn];
#pragma unroll
            for (int r = 0; r < 4; ++r) {
                int gm = m0 + wr + i * 16 + quad * 4 + r;
                if (gm >= M_ROWS) continue;
                int bb = gm / 197;
                int tok = gm - bb * 197;
                float val = acc[i][j][r] + bv;
                if (which == 0) val *= 0.125f;
                size_t dst = (size_t)which * QSZ +
                             ((size_t)((bb * 12 + hh) * 197 + tok) * 64 + dd);
                qkv[dst] = f2bf(val);
            }
        }
    }
}

// ---------------- Kernel 3: attention, one block per head; K + V^T staged in LDS ----------
__global__ __launch_bounds__(256, 2) void attn_kernel(
        const unsigned short* __restrict__ qkv, float* __restrict__ out) {
    __shared__ __align__(16) unsigned short Ks[197 * 72];     // 28368 B
    __shared__ __align__(16) unsigned short Vt[64 * 216];     // 27648 B (stride 216: 2-way banks)
    __shared__ __align__(16) unsigned short Ps[4 * 16 * 136]; // 17408 B

    const int g = blockIdx.x;            // head index b*12+h
    const int b = g / 12, h = g - b * 12;
    const int t = threadIdx.x, w = t >> 6, lane = t & 63;
    const int quad = lane >> 4, l16 = lane & 15;

    const size_t headoff = (size_t)(g * 197) * 64;
    const unsigned short* Qg = qkv + headoff;
    const unsigned short* Kg = qkv + (size_t)QSZ + headoff;
    const unsigned short* Vg = qkv + (size_t)2 * QSZ + headoff;

    // stage K coalesced: 197 rows x 64 d, 16B chunks
    for (int idx = t; idx < 1576; idx += 256) {
        int row = idx >> 3, c8 = (idx & 7) * 8;
        *(uint4*)&Ks[row * 72 + c8] = *(const uint4*)(Kg + (size_t)row * 64 + c8);
    }
    // zero Vt pad cols 197..215 (PV reads them where p==0; avoid NaN*0)
    for (int idx = t; idx < 64 * 19; idx += 256) {
        int d = idx / 19, c = 197 + idx - d * 19;
        Vt[d * 216 + c] = 0;
    }
    // stage V transposed: coalesced 16B global read, scalar LDS scatter
    for (int idx = t; idx < 1576; idx += 256) {
        int tok = idx >> 3, d0 = (idx & 7) * 8;
        ushort4 v0 = *(const ushort4*)(Vg + (size_t)tok * 64 + d0);
        ushort4 v1 = *(const ushort4*)(Vg + (size_t)tok * 64 + d0 + 4);
        Vt[(d0 + 0) * 216 + tok] = v0.x;
        Vt[(d0 + 1) * 216 + tok] = v0.y;
        Vt[(d0 + 2) * 216 + tok] = v0.z;
        Vt[(d0 + 3) * 216 + tok] = v0.w;
        Vt[(d0 + 4) * 216 + tok] = v1.x;
        Vt[(d0 + 5) * 216 + tok] = v1.y;
        Vt[(d0 + 6) * 216 + tok] = v1.z;
        Vt[(d0 + 7) * 216 + tok] = v1.w;
    }
    __syncthreads();

    unsigned short* Pw = Ps + w * (16 * 136);

    // wave w handles q-tiles w, w+4, w+8, w+12 (13 tiles of 16 rows)
    for (int tile = w; tile < 13; tile += 4) {
        int rq = tile * 16 + l16;
        int tokq = rq < 197 ? rq : 196;
        bf16x8 aq0 = *(const bf16x8*)(Qg + (size_t)tokq * 64 + quad * 8);
        bf16x8 aq1 = *(const bf16x8*)(Qg + (size_t)tokq * 64 + 32 + quad * 8);

        // scores: 13 chunks of 16 kt-cols, K fragments from LDS
        f32x4 s[13];
        __builtin_amdgcn_s_setprio(1);
#pragma unroll
        for (int c = 0; c < 13; ++c) {
            int krow = c * 16 + l16;
            if (krow > 196) krow = 196;             // clamped read; masked below
            bf16x8 kb0 = *(const bf16x8*)&Ks[krow * 72 + quad * 8];
            bf16x8 kb1 = *(const bf16x8*)&Ks[krow * 72 + 32 + quad * 8];
            f32x4 zz = (f32x4){0.f, 0.f, 0.f, 0.f};
            zz = __builtin_amdgcn_mfma_f32_16x16x32_bf16(aq0, kb0, zz, 0, 0, 0);
            zz = __builtin_amdgcn_mfma_f32_16x16x32_bf16(aq1, kb1, zz, 0, 0, 0);
            s[c] = zz;
        }
        __builtin_amdgcn_s_setprio(0);
        if (l16 >= 5) { s[12][0] = -1e30f; s[12][1] = -1e30f; s[12][2] = -1e30f; s[12][3] = -1e30f; }

        // softmax over 208 cols (rows = quad*4+r, cols spread over l16)
        float mx[4], lsum[4];
#pragma unroll
        for (int r = 0; r < 4; ++r) {
            float m = s[0][r];
#pragma unroll
            for (int c = 1; c < 13; ++c) m = fmaxf(m, s[c][r]);
#pragma unroll
            for (int d = 1; d < 16; d <<= 1) m = fmaxf(m, __shfl_xor(m, d));
            mx[r] = m;
            lsum[r] = 0.f;
        }
#pragma unroll
        for (int c = 0; c < 13; ++c)
#pragma unroll
            for (int r = 0; r < 4; ++r) {
                float p = __expf(s[c][r] - mx[r]);
                s[c][r] = p;
                lsum[r] += p;
            }
#pragma unroll
        for (int r = 0; r < 4; ++r)
#pragma unroll
            for (int d = 1; d < 16; d <<= 1) lsum[r] += __shfl_xor(lsum[r], d);

        f32x4 o[4];
#pragma unroll
        for (int j = 0; j < 4; ++j) o[j] = (f32x4){0.f, 0.f, 0.f, 0.f};

        // PV pass 1: P cols 0..127 (same-wave LDS round trip, no barrier)
#pragma unroll
        for (int c = 0; c < 8; ++c)
#pragma unroll
            for (int r = 0; r < 4; ++r)
                Pw[(quad * 4 + r) * 136 + c * 16 + l16] = f2bf(s[c][r]);
        __builtin_amdgcn_s_setprio(1);
#pragma unroll
        for (int kc = 0; kc < 4; ++kc) {
            int kof = kc * 32 + quad * 8;
            bf16x8 ap = *(const bf16x8*)&Pw[l16 * 136 + kof];
#pragma unroll
            for (int j = 0; j < 4; ++j) {
                bf16x8 bv = *(const bf16x8*)&Vt[(j * 16 + l16) * 216 + kof];
                o[j] = __builtin_amdgcn_mfma_f32_16x16x32_bf16(ap, bv, o[j], 0, 0, 0);
            }
        }
        __builtin_amdgcn_s_setprio(0);
        // PV pass 2: P cols 128..207 -> buffer cols 0..79; cols 80..95 zeroed (p==0)
#pragma unroll
        for (int r = 0; r < 4; ++r)
            Pw[(quad * 4 + r) * 136 + 80 + l16] = 0;
#pragma unroll
        for (int c = 8; c < 13; ++c)
#pragma unroll
            for (int r = 0; r < 4; ++r)
                Pw[(quad * 4 + r) * 136 + (c - 8) * 16 + l16] = f2bf(s[c][r]);
        __builtin_amdgcn_s_setprio(1);
#pragma unroll
        for (int kc = 0; kc < 3; ++kc) {
            int kofA = kc * 32 + quad * 8;
            // kc==2, quad>=2 -> kt 208..223 where p==0 exactly; clamp LDS read in-range
            int kofB = (kc == 2 && quad >= 2) ? 0 : kofA;
            bf16x8 ap = *(const bf16x8*)&Pw[l16 * 136 + kofA];
#pragma unroll
            for (int j = 0; j < 4; ++j) {
                bf16x8 bv = *(const bf16x8*)&Vt[(j * 16 + l16) * 216 + 128 + kofB];
                o[j] = __builtin_amdgcn_mfma_f32_16x16x32_bf16(ap, bv, o[j], 0, 0, 0);
            }
        }
        __builtin_amdgcn_s_setprio(0);

        // epilogue: divide by l, store fp32 [B, tok, 768]
        int tokbase = tile * 16 + quad * 4;
#pragma unroll
        for (int r = 0; r < 4; ++r) {
            int tr = tokbase + r;
            if (tr >= 197) continue;
            float inv = 1.f / lsum[r];
#pragma unroll
            for (int j = 0; j < 4; ++j)
                out[((size_t)(b * 197 + tr)) * 768 + h * 64 + j * 16 + l16] = o[j][r] * inv;
        }
    }
}

extern "C" void kernel_launch(void* const* d_in, const int* in_sizes, int n_in,
                              void* d_out, int out_size, void* d_ws, size_t ws_size,
                              hipStream_t stream) {
    const float* X    = (const float*)d_in[0];   // [64,197,768]
    const float* W    = (const float*)d_in[1];   // [768,2304]
    const float* bias = (const float*)d_in[2];   // [2304]
    unsigned short* ws = (unsigned short*)d_ws;  // q | k | v planes
    float* out = (float*)d_out;                  // [64,197,768]

    // Xb and Wt live in d_out's dead space (overwritten by attn at the end).
    unsigned short* Xb = (unsigned short*)d_out;
    unsigned short* Wt = (unsigned short*)d_out + XB_ELEMS;

    prep_kernel<<<6528, 256, 0, stream>>>(X, Xb, W, Wt);
    qkv_gemm_kernel<<<900, 512, 0, stream>>>(Xb, Wt, bias, ws);
    attn_kernel<<<768, 256, 0, stream>>>(ws, out);
}

// Round 8
// 217.634 us; speedup vs baseline: 1.1558x; 1.1558x over previous
//
#include <hip/hip_runtime.h>

#define M_ROWS 12608          // 64*197
#define K_DIM  768
#define XB_ELEMS (12800*768)  // padded bf16 X copy (lives in d_ws)

typedef __bf16 bf16x8 __attribute__((ext_vector_type(8)));
typedef float  f32x4  __attribute__((ext_vector_type(4)));

__device__ __forceinline__ unsigned short f2bf(float f) {
    unsigned u = __builtin_bit_cast(unsigned, f);
    u += 0x7fffu + ((u >> 16) & 1u);          // RNE, inputs are finite
    return (unsigned short)(u >> 16);
}

__device__ __forceinline__ void gll16(const unsigned short* g, unsigned short* l) {
    __builtin_amdgcn_global_load_lds(
        (const __attribute__((address_space(1))) unsigned int*)g,
        (__attribute__((address_space(3))) unsigned int*)l, 16, 0, 0);
}

// ---------------- Kernel 0: fused prep — X fp32->bf16 (padded) AND W transpose ---------
// Blocks 0..4799: x2bf to 12800 rows (pad rows zeroed). Blocks 4800..6527: wtrans.
__global__ __launch_bounds__(256) void prep_kernel(
        const float* __restrict__ X, unsigned short* __restrict__ Xb,
        const float* __restrict__ W, unsigned short* __restrict__ Wt) {
    __shared__ float tile[32][33];
    const int bid = blockIdx.x;
    if (bid < 4800) {
        size_t base = ((size_t)bid * 256 + threadIdx.x) * 8;
        if (base >= (size_t)M_ROWS * K_DIM) {   // zero pad rows 12608..12799
            *(ushort4*)(Xb + base) = (ushort4){0, 0, 0, 0};
            *(ushort4*)(Xb + base + 4) = (ushort4){0, 0, 0, 0};
            return;
        }
        float4 a = *(const float4*)(X + base);
        float4 b = *(const float4*)(X + base + 4);
        ushort4 lo, hi;
        lo.x = f2bf(a.x); lo.y = f2bf(a.y); lo.z = f2bf(a.z); lo.w = f2bf(a.w);
        hi.x = f2bf(b.x); hi.y = f2bf(b.y); hi.z = f2bf(b.z); hi.w = f2bf(b.w);
        *(ushort4*)(Xb + base) = lo;
        *(ushort4*)(Xb + base + 4) = hi;
        return;
    }
    const int b2 = bid - 4800;
    const int n0 = (b2 % 72) * 32, k0 = (b2 / 72) * 32;
    const int tx = threadIdx.x & 31, ty = threadIdx.x >> 5;
#pragma unroll
    for (int i = 0; i < 4; ++i)
        tile[ty + i * 8][tx] = W[(size_t)(k0 + ty + i * 8) * 2304 + n0 + tx];
    __syncthreads();
#pragma unroll
    for (int i = 0; i < 4; ++i)
        Wt[(size_t)(n0 + ty + i * 8) * K_DIM + k0 + tx] = f2bf(tile[tx][ty + i * 8]);
}

// ---------------- Kernel 1: FUSED per-head QKV-GEMM + attention ------------------------
// One block per (batch, head): GEMM C[256pad x 192] = X[b] (256x768, rows>=197 garbage)
// @ Wh (768x192: q|k|v column groups), accumulated in registers over the R3-proven
// 2-buffer LDS ring (24 steps of BK=32); epilogue adds bias, scales q by 1/8, writes
// q->Qs, k->Ks (row-major, stride 72), v->Vt (transposed, stride 216) in LDS; then the
// proven attn phase runs in-place (no qkv global round trip, no kernel boundary).
// 8 waves: GEMM wave grid 4M x 2N (64 rows x 96 cols each); attn: q-tiles w, w+8.
// LDS 141.7 KB -> 1 block/CU; grid 768 = 3 exact occupancy rounds, no tail.
// LDS map (shorts): A dbuf [0,16384) | B dbuf [16384,28672) | Qs 28672 | Ks 42856 |
// Vt 57040..70864; Ps (8 x 16 x 136 = 17408) aliases the dead A/B staging after GEMM.
__global__ __launch_bounds__(512, 2) void fused_kernel(
        const unsigned short* __restrict__ Xb, const unsigned short* __restrict__ Wt,
        const float* __restrict__ bias, float* __restrict__ out) {
    __shared__ __align__(16) unsigned short L[70864];   // 141728 B

    const int t = threadIdx.x;
    const int w = t >> 6, lane = t & 63, quad = lane >> 4, l16 = lane & 15;
    const int wrow0 = (w >> 1) * 64;    // GEMM: M rows owned (64)
    const int wcol0 = (w & 1) * 96;     // GEMM: N cols owned (96)

    // XCD-chunked bijective swizzle (768 = 8*96): each batch's 12 heads on one XCD
    const int lin = blockIdx.x;
    const int wg = (lin & 7) * 96 + (lin >> 3);
    const int bb = wg / 12, h = wg - bb * 12;

    const unsigned short* XbB = Xb + (size_t)(bb * 197) * K_DIM;

    // staging chunk table: waves 0-3 stage A (4 chunks: kc=w, rowgroup=s),
    // waves 4-7 stage B (3 chunks: idx=(w-4)*3+s -> kc=idx&3, whichgroup=idx>>2)
    const unsigned short* sgp[4];
    int sof[4];
    const int nst = (w < 4) ? 4 : 3;
    const int bstride = (w < 4) ? 8192 : 6144;
    if (w < 4) {
#pragma unroll
        for (int s = 0; s < 4; ++s) {
            sgp[s] = XbB + (size_t)(s * 64 + lane) * K_DIM + w * 8;
            sof[s] = w * 2048 + s * 512;
        }
    } else {
#pragma unroll
        for (int s = 0; s < 3; ++s) {
            const int idx = (w - 4) * 3 + s;
            const int kc = idx & 3, grp = idx >> 2;
            sgp[s] = Wt + (size_t)(grp * 768 + h * 64 + lane) * K_DIM + kc * 8;
            sof[s] = 16384 + kc * 1536 + grp * 512;
        }
        sgp[3] = sgp[0]; sof[3] = sof[0];
    }

    f32x4 acc[4][6];
#pragma unroll
    for (int i = 0; i < 4; ++i)
#pragma unroll
        for (int j = 0; j < 6; ++j) acc[i][j] = (f32x4){0.f, 0.f, 0.f, 0.f};

    // prologue: stage tile 0, land it
#pragma unroll
    for (int s = 0; s < 4; ++s)
        if (s < nst) gll16(sgp[s], &L[sof[s]]);
    asm volatile("s_waitcnt vmcnt(0)" ::: "memory");
    __builtin_amdgcn_s_barrier();
    asm volatile("" ::: "memory");

#pragma unroll 2
    for (int kt = 0; kt < 24; ++kt) {
        const int cur = kt & 1, nxt = cur ^ 1;
        const int sk = (kt + 1 < 24 ? kt + 1 : 0) * 32;   // tail: dummy restage (dead)

        // issue next tile's staging first; body below overlaps its latency
#pragma unroll
        for (int s = 0; s < 4; ++s)
            if (s < nst) gll16(sgp[s] + sk, &L[sof[s] + nxt * bstride]);

        const unsigned short* Ab = &L[cur * 8192];
        const unsigned short* Bb = &L[16384 + cur * 6144];
        bf16x8 af[4], bq[6];
#pragma unroll
        for (int i = 0; i < 4; ++i)
            af[i] = *(const bf16x8*)&Ab[quad * 2048 + (wrow0 + i * 16 + l16) * 8];
#pragma unroll
        for (int j = 0; j < 6; ++j)
            bq[j] = *(const bf16x8*)&Bb[quad * 1536 + (wcol0 + j * 16 + l16) * 8];

#pragma unroll
        for (int i = 0; i < 4; ++i)
#pragma unroll
            for (int j = 0; j < 6; ++j)
                acc[i][j] = __builtin_amdgcn_mfma_f32_16x16x32_bf16(af[i], bq[j], acc[i][j], 0, 0, 0);

        asm volatile("s_waitcnt vmcnt(0)" ::: "memory");
        __builtin_amdgcn_s_barrier();
        asm volatile("" ::: "memory");
    }

    unsigned short* Qs = &L[28672];   // [197][72]
    unsigned short* Ks = &L[42856];   // [197][72]
    unsigned short* Vt = &L[57040];   // [64][216] transposed
    unsigned short* Ps = &L[0];       // aliases dead staging (17408 shorts)

    // epilogue: bias, q-scale, scatter to Qs/Ks/Vt (rows >= 197 discarded)
#pragma unroll
    for (int j = 0; j < 6; ++j) {
        const int gnr = wcol0 + j * 16 + l16;   // 0..191
        const int which = gnr >> 6, d = gnr & 63;
        const float bv = bias[which * 768 + h * 64 + d];
#pragma unroll
        for (int i = 0; i < 4; ++i) {
            const int rowb = wrow0 + i * 16 + quad * 4;
#pragma unroll
            for (int r = 0; r < 4; ++r) {
                const int row = rowb + r;
                if (row >= 197) continue;
                const float val = acc[i][j][r] + bv;
                if (which == 0)      Qs[row * 72 + d] = f2bf(val * 0.125f);
                else if (which == 1) Ks[row * 72 + d] = f2bf(val);
                else                 Vt[d * 216 + row] = f2bf(val);
            }
        }
    }
    // zero Vt pad cols 197..215 (PV reads them where p==0; avoid NaN*0)
    for (int idx = t; idx < 64 * 19; idx += 512) {
        int d = idx / 19, c = 197 + idx - d * 19;
        Vt[d * 216 + c] = 0;
    }
    __syncthreads();

    // ---------------- attention phase (proven structure; Q/K/V already in LDS) --------
    unsigned short* Pw = Ps + w * (16 * 136);

    for (int tile = w; tile < 13; tile += 8) {
        int rq = tile * 16 + l16;
        int tokq = rq < 197 ? rq : 196;
        bf16x8 aq0 = *(const bf16x8*)&Qs[tokq * 72 + quad * 8];
        bf16x8 aq1 = *(const bf16x8*)&Qs[tokq * 72 + 32 + quad * 8];

        // scores: 13 chunks of 16 kt-cols, K fragments from LDS
        f32x4 s[13];
        __builtin_amdgcn_s_setprio(1);
#pragma unroll
        for (int c = 0; c < 13; ++c) {
            int krow = c * 16 + l16;
            if (krow > 196) krow = 196;             // clamped read; masked below
            bf16x8 kb0 = *(const bf16x8*)&Ks[krow * 72 + quad * 8];
            bf16x8 kb1 = *(const bf16x8*)&Ks[krow * 72 + 32 + quad * 8];
            f32x4 zz = (f32x4){0.f, 0.f, 0.f, 0.f};
            zz = __builtin_amdgcn_mfma_f32_16x16x32_bf16(aq0, kb0, zz, 0, 0, 0);
            zz = __builtin_amdgcn_mfma_f32_16x16x32_bf16(aq1, kb1, zz, 0, 0, 0);
            s[c] = zz;
        }
        __builtin_amdgcn_s_setprio(0);
        if (l16 >= 5) { s[12][0] = -1e30f; s[12][1] = -1e30f; s[12][2] = -1e30f; s[12][3] = -1e30f; }

        // softmax over 208 cols (rows = quad*4+r, cols spread over l16)
        float mx[4], lsum[4];
#pragma unroll
        for (int r = 0; r < 4; ++r) {
            float m = s[0][r];
#pragma unroll
            for (int c = 1; c < 13; ++c) m = fmaxf(m, s[c][r]);
#pragma unroll
            for (int d = 1; d < 16; d <<= 1) m = fmaxf(m, __shfl_xor(m, d));
            mx[r] = m;
            lsum[r] = 0.f;
        }
#pragma unroll
        for (int c = 0; c < 13; ++c)
#pragma unroll
            for (int r = 0; r < 4; ++r) {
                float p = __expf(s[c][r] - mx[r]);
                s[c][r] = p;
                lsum[r] += p;
            }
#pragma unroll
        for (int r = 0; r < 4; ++r)
#pragma unroll
            for (int d = 1; d < 16; d <<= 1) lsum[r] += __shfl_xor(lsum[r], d);

        f32x4 o[4];
#pragma unroll
        for (int j = 0; j < 4; ++j) o[j] = (f32x4){0.f, 0.f, 0.f, 0.f};

        // PV pass 1: P cols 0..127 (same-wave LDS round trip, no barrier)
#pragma unroll
        for (int c = 0; c < 8; ++c)
#pragma unroll
            for (int r = 0; r < 4; ++r)
                Pw[(quad * 4 + r) * 136 + c * 16 + l16] = f2bf(s[c][r]);
        __builtin_amdgcn_s_setprio(1);
#pragma unroll
        for (int kc = 0; kc < 4; ++kc) {
            int kof = kc * 32 + quad * 8;
            bf16x8 ap = *(const bf16x8*)&Pw[l16 * 136 + kof];
#pragma unroll
            for (int j = 0; j < 4; ++j) {
                bf16x8 bv = *(const bf16x8*)&Vt[(j * 16 + l16) * 216 + kof];
                o[j] = __builtin_amdgcn_mfma_f32_16x16x32_bf16(ap, bv, o[j], 0, 0, 0);
            }
        }
        __builtin_amdgcn_s_setprio(0);
        // PV pass 2: P cols 128..207 -> buffer cols 0..79; cols 80..95 zeroed (p==0)
#pragma unroll
        for (int r = 0; r < 4; ++r)
            Pw[(quad * 4 + r) * 136 + 80 + l16] = 0;
#pragma unroll
        for (int c = 8; c < 13; ++c)
#pragma unroll
            for (int r = 0; r < 4; ++r)
                Pw[(quad * 4 + r) * 136 + (c - 8) * 16 + l16] = f2bf(s[c][r]);
        __builtin_amdgcn_s_setprio(1);
#pragma unroll
        for (int kc = 0; kc < 3; ++kc) {
            int kofA = kc * 32 + quad * 8;
            // kc==2, quad>=2 -> kt 208..223 where p==0 exactly; clamp LDS read in-range
            int kofB = (kc == 2 && quad >= 2) ? 0 : kofA;
            bf16x8 ap = *(const bf16x8*)&Pw[l16 * 136 + kofA];
#pragma unroll
            for (int j = 0; j < 4; ++j) {
                bf16x8 bv = *(const bf16x8*)&Vt[(j * 16 + l16) * 216 + 128 + kofB];
                o[j] = __builtin_amdgcn_mfma_f32_16x16x32_bf16(ap, bv, o[j], 0, 0, 0);
            }
        }
        __builtin_amdgcn_s_setprio(0);

        // epilogue: divide by l, store fp32 [B, tok, 768]
        int tokbase = tile * 16 + quad * 4;
#pragma unroll
        for (int r = 0; r < 4; ++r) {
            int tr = tokbase + r;
            if (tr >= 197) continue;
            float inv = 1.f / lsum[r];
#pragma unroll
            for (int j = 0; j < 4; ++j)
                out[((size_t)(bb * 197 + tr)) * 768 + h * 64 + j * 16 + l16] = o[j][r] * inv;
        }
    }
}

extern "C" void kernel_launch(void* const* d_in, const int* in_sizes, int n_in,
                              void* d_out, int out_size, void* d_ws, size_t ws_size,
                              hipStream_t stream) {
    const float* X    = (const float*)d_in[0];   // [64,197,768]
    const float* W    = (const float*)d_in[1];   // [768,2304]
    const float* bias = (const float*)d_in[2];   // [2304]
    float* out = (float*)d_out;                  // [64,197,768]

    // Xb and Wt live in d_ws (out overlaps the old d_out scratch -> must not alias)
    unsigned short* Xb = (unsigned short*)d_ws;
    unsigned short* Wt = (unsigned short*)d_ws + XB_ELEMS;

    prep_kernel<<<6528, 256, 0, stream>>>(X, Xb, W, Wt);
    fused_kernel<<<768, 512, 0, stream>>>(Xb, Wt, bias, out);
}

// Round 9
// 201.211 us; speedup vs baseline: 1.2502x; 1.0816x over previous
//
#include <hip/hip_runtime.h>

#define M_ROWS 12608          // 64*197
#define K_DIM  768
// Xc: 64 panels x 24 kt x 16 chunks x 512 shorts (chunk = [lane64][k8]) = 25.2 MB
#define XC_ELEMS (64*24*16*512)
// Wc: 12 heads x 24 kt x 12 chunks x 512 shorts = 3.5 MB
#define WC_ELEMS (12*24*12*512)

typedef __bf16 bf16x8 __attribute__((ext_vector_type(8)));
typedef float  f32x4  __attribute__((ext_vector_type(4)));

__device__ __forceinline__ unsigned short f2bf(float f) {
    unsigned u = __builtin_bit_cast(unsigned, f);
    u += 0x7fffu + ((u >> 16) & 1u);          // RNE, inputs are finite
    return (unsigned short)(u >> 16);
}

__device__ __forceinline__ void gll16(const unsigned short* g, unsigned short* l) {
    __builtin_amdgcn_global_load_lds(
        (const __attribute__((address_space(1))) unsigned int*)g,
        (__attribute__((address_space(3))) unsigned int*)l, 16, 0, 0);
}

// ---------------- Kernel 0: prep — emit X and W in GEMM-staging chunk order -----------
// Xc chunk (p, kt, c= kc*4+rg): lane l holds X[p*197 + rg*64 + l][kt*32 + kc*8 + 0..7]
//   (rows >= 12608 zero-filled). Each chunk is 1 KB CONTIGUOUS = one fully-coalesced
//   global_load_lds in the fused kernel (lane i at base + i*16B), vs the previous
//   1536-B-stride scatter (64 lines/instr). Blocks 0..6143: 4 chunks each.
// Wc chunk (h, kt, cB= kc*3+grp): lane l holds W[kt*32+kc*8+0..7][grp*768 + h*64 + l].
//   Blocks 6144..7871: one 32x32 W tile via LDS transpose -> half-chunks of 4 kc.
__global__ __launch_bounds__(256) void prep_kernel(
        const float* __restrict__ X, unsigned short* __restrict__ Xc,
        const float* __restrict__ W, unsigned short* __restrict__ Wc) {
    __shared__ float tile[32][33];
    const int bid = blockIdx.x;
    const int t = threadIdx.x;
    if (bid < 6144) {
        const int cg = bid * 4 + (t >> 6);      // global chunk id
        const int lane = t & 63;
        const int p = cg / 384, rem = cg - p * 384;
        const int kt = rem >> 4, c = rem & 15;
        const int kc = c >> 2, rg = c & 3;
        const int grow = p * 197 + rg * 64 + lane;
        uint4 u = (uint4){0, 0, 0, 0};
        if (grow < M_ROWS) {
            const float* src = X + (size_t)grow * K_DIM + kt * 32 + kc * 8;
            float4 a = *(const float4*)src;
            float4 b = *(const float4*)(src + 4);
            u.x = f2bf(a.x) | ((unsigned)f2bf(a.y) << 16);
            u.y = f2bf(a.z) | ((unsigned)f2bf(a.w) << 16);
            u.z = f2bf(b.x) | ((unsigned)f2bf(b.y) << 16);
            u.w = f2bf(b.z) | ((unsigned)f2bf(b.w) << 16);
        }
        *(uint4*)(Xc + (size_t)cg * 512 + lane * 8) = u;
        return;
    }
    const int b2 = bid - 6144;
    const int n0 = (b2 % 72) * 32, k0 = (b2 / 72) * 32;
    const int tx = t & 31, ty = t >> 5;
#pragma unroll
    for (int i = 0; i < 4; ++i)
        tile[ty + i * 8][tx] = W[(size_t)(k0 + ty + i * 8) * 2304 + n0 + tx];   // [klocal][nlocal]
    __syncthreads();
    if (t < 128) {
        const int kc = t >> 5, tx2 = t & 31;
        const int grp = n0 / 768, remn = n0 - grp * 768;
        const int h = remn >> 6, lh = remn & 63;    // 0 or 32
        const int kt = k0 >> 5;
        uint4 u;
        u.x = f2bf(tile[kc * 8 + 0][tx2]) | ((unsigned)f2bf(tile[kc * 8 + 1][tx2]) << 16);
        u.y = f2bf(tile[kc * 8 + 2][tx2]) | ((unsigned)f2bf(tile[kc * 8 + 3][tx2]) << 16);
        u.z = f2bf(tile[kc * 8 + 4][tx2]) | ((unsigned)f2bf(tile[kc * 8 + 5][tx2]) << 16);
        u.w = f2bf(tile[kc * 8 + 6][tx2]) | ((unsigned)f2bf(tile[kc * 8 + 7][tx2]) << 16);
        *(uint4*)(Wc + (size_t)(((h * 24 + kt) * 12) + kc * 3 + grp) * 512 + (lh + tx2) * 8) = u;
    }
}

// ---------------- Kernel 1: FUSED per-head QKV-GEMM + attention ------------------------
// Identical to the R8 kernel (passed, 137.5us) EXCEPT the staging sources: every
// global_load_lds now reads a 1-KB CONTIGUOUS chunk from Xc/Wc (lane i at base+i*16B)
// instead of 64 scattered 16-B requests at 1536-B stride. LDS image, ds_reads, MFMA
// mapping, epilogue, attn phase: byte-identical.
// LDS map (shorts): A dbuf [0,16384) | B dbuf [16384,28672) | Qs 28672 | Ks 42856 |
// Vt 57040..70864; Ps (17408 shorts) aliases the dead A/B staging after GEMM.
__global__ __launch_bounds__(512, 2) void fused_kernel(
        const unsigned short* __restrict__ Xc, const unsigned short* __restrict__ Wc,
        const float* __restrict__ bias, float* __restrict__ out) {
    __shared__ __align__(16) unsigned short L[70864];   // 141728 B

    const int t = threadIdx.x;
    const int w = t >> 6, lane = t & 63, quad = lane >> 4, l16 = lane & 15;
    const int wrow0 = (w >> 1) * 64;    // GEMM: M rows owned (64)
    const int wcol0 = (w & 1) * 96;     // GEMM: N cols owned (96)

    // XCD-chunked bijective swizzle (768 = 8*96): each batch's 12 heads on one XCD
    const int lin = blockIdx.x;
    const int wg = (lin & 7) * 96 + (lin >> 3);
    const int bb = wg / 12, h = wg - bb * 12;

    // staging chunk table: waves 0-3 stage A (4 chunks, c = w*4+s), waves 4-7 stage B
    // (3 chunks, cB = kc*3+grp for idx=(w-4)*3+s). All sources contiguous 1 KB.
    const unsigned short* sgp[4];
    int sof[4];
    const int nst = (w < 4) ? 4 : 3;
    const int bstride = (w < 4) ? 8192 : 6144;          // LDS dbuf stride (shorts)
    const int kstride = (w < 4) ? 8192 : 6144;          // global per-kt stride (shorts)
    if (w < 4) {
#pragma unroll
        for (int s = 0; s < 4; ++s) {
            sgp[s] = Xc + ((size_t)(bb * 24) * 16 + w * 4 + s) * 512 + lane * 8;
            sof[s] = (w * 4 + s) * 512;
        }
    } else {
#pragma unroll
        for (int s = 0; s < 3; ++s) {
            const int idx = (w - 4) * 3 + s;
            const int kc = idx & 3, grp = idx >> 2;
            sgp[s] = Wc + ((size_t)(h * 24) * 12 + kc * 3 + grp) * 512 + lane * 8;
            sof[s] = 16384 + (kc * 3 + grp) * 512;
        }
        sgp[3] = sgp[0]; sof[3] = sof[0];
    }

    f32x4 acc[4][6];
#pragma unroll
    for (int i = 0; i < 4; ++i)
#pragma unroll
        for (int j = 0; j < 6; ++j) acc[i][j] = (f32x4){0.f, 0.f, 0.f, 0.f};

    // prologue: stage tile 0, land it
#pragma unroll
    for (int s = 0; s < 4; ++s)
        if (s < nst) gll16(sgp[s], &L[sof[s]]);
    asm volatile("s_waitcnt vmcnt(0)" ::: "memory");
    __builtin_amdgcn_s_barrier();
    asm volatile("" ::: "memory");

#pragma unroll 2
    for (int kt = 0; kt < 24; ++kt) {
        const int cur = kt & 1, nxt = cur ^ 1;
        const int sk = (kt + 1 < 24 ? kt + 1 : 0) * kstride;   // tail: dummy restage

        // issue next tile's staging first; body below overlaps its latency
#pragma unroll
        for (int s = 0; s < 4; ++s)
            if (s < nst) gll16(sgp[s] + sk, &L[sof[s] + nxt * bstride]);

        const unsigned short* Ab = &L[cur * 8192];
        const unsigned short* Bb = &L[16384 + cur * 6144];
        bf16x8 af[4], bq[6];
#pragma unroll
        for (int i = 0; i < 4; ++i)
            af[i] = *(const bf16x8*)&Ab[quad * 2048 + (wrow0 + i * 16 + l16) * 8];
#pragma unroll
        for (int j = 0; j < 6; ++j)
            bq[j] = *(const bf16x8*)&Bb[quad * 1536 + (wcol0 + j * 16 + l16) * 8];

#pragma unroll
        for (int i = 0; i < 4; ++i)
#pragma unroll
            for (int j = 0; j < 6; ++j)
                acc[i][j] = __builtin_amdgcn_mfma_f32_16x16x32_bf16(af[i], bq[j], acc[i][j], 0, 0, 0);

        asm volatile("s_waitcnt vmcnt(0)" ::: "memory");
        __builtin_amdgcn_s_barrier();
        asm volatile("" ::: "memory");
    }

    unsigned short* Qs = &L[28672];   // [197][72]
    unsigned short* Ks = &L[42856];   // [197][72]
    unsigned short* Vt = &L[57040];   // [64][216] transposed
    unsigned short* Ps = &L[0];       // aliases dead staging (17408 shorts)

    // epilogue: bias, q-scale, scatter to Qs/Ks/Vt (rows >= 197 discarded)
#pragma unroll
    for (int j = 0; j < 6; ++j) {
        const int gnr = wcol0 + j * 16 + l16;   // 0..191
        const int which = gnr >> 6, d = gnr & 63;
        const float bv = bias[which * 768 + h * 64 + d];
#pragma unroll
        for (int i = 0; i < 4; ++i) {
            const int rowb = wrow0 + i * 16 + quad * 4;
#pragma unroll
            for (int r = 0; r < 4; ++r) {
                const int row = rowb + r;
                if (row >= 197) continue;
                const float val = acc[i][j][r] + bv;
                if (which == 0)      Qs[row * 72 + d] = f2bf(val * 0.125f);
                else if (which == 1) Ks[row * 72 + d] = f2bf(val);
                else                 Vt[d * 216 + row] = f2bf(val);
            }
        }
    }
    // zero Vt pad cols 197..215 (PV reads them where p==0; avoid NaN*0)
    for (int idx = t; idx < 64 * 19; idx += 512) {
        int d = idx / 19, c = 197 + idx - d * 19;
        Vt[d * 216 + c] = 0;
    }
    __syncthreads();

    // ---------------- attention phase (proven structure; Q/K/V already in LDS) --------
    unsigned short* Pw = Ps + w * (16 * 136);

    for (int tile = w; tile < 13; tile += 8) {
        int rq = tile * 16 + l16;
        int tokq = rq < 197 ? rq : 196;
        bf16x8 aq0 = *(const bf16x8*)&Qs[tokq * 72 + quad * 8];
        bf16x8 aq1 = *(const bf16x8*)&Qs[tokq * 72 + 32 + quad * 8];

        // scores: 13 chunks of 16 kt-cols, K fragments from LDS
        f32x4 s[13];
        __builtin_amdgcn_s_setprio(1);
#pragma unroll
        for (int c = 0; c < 13; ++c) {
            int krow = c * 16 + l16;
            if (krow > 196) krow = 196;             // clamped read; masked below
            bf16x8 kb0 = *(const bf16x8*)&Ks[krow * 72 + quad * 8];
            bf16x8 kb1 = *(const bf16x8*)&Ks[krow * 72 + 32 + quad * 8];
            f32x4 zz = (f32x4){0.f, 0.f, 0.f, 0.f};
            zz = __builtin_amdgcn_mfma_f32_16x16x32_bf16(aq0, kb0, zz, 0, 0, 0);
            zz = __builtin_amdgcn_mfma_f32_16x16x32_bf16(aq1, kb1, zz, 0, 0, 0);
            s[c] = zz;
        }
        __builtin_amdgcn_s_setprio(0);
        if (l16 >= 5) { s[12][0] = -1e30f; s[12][1] = -1e30f; s[12][2] = -1e30f; s[12][3] = -1e30f; }

        // softmax over 208 cols (rows = quad*4+r, cols spread over l16)
        float mx[4], lsum[4];
#pragma unroll
        for (int r = 0; r < 4; ++r) {
            float m = s[0][r];
#pragma unroll
            for (int c = 1; c < 13; ++c) m = fmaxf(m, s[c][r]);
#pragma unroll
            for (int d = 1; d < 16; d <<= 1) m = fmaxf(m, __shfl_xor(m, d));
            mx[r] = m;
            lsum[r] = 0.f;
        }
#pragma unroll
        for (int c = 0; c < 13; ++c)
#pragma unroll
            for (int r = 0; r < 4; ++r) {
                float p = __expf(s[c][r] - mx[r]);
                s[c][r] = p;
                lsum[r] += p;
            }
#pragma unroll
        for (int r = 0; r < 4; ++r)
#pragma unroll
            for (int d = 1; d < 16; d <<= 1) lsum[r] += __shfl_xor(lsum[r], d);

        f32x4 o[4];
#pragma unroll
        for (int j = 0; j < 4; ++j) o[j] = (f32x4){0.f, 0.f, 0.f, 0.f};

        // PV pass 1: P cols 0..127 (same-wave LDS round trip, no barrier)
#pragma unroll
        for (int c = 0; c < 8; ++c)
#pragma unroll
            for (int r = 0; r < 4; ++r)
                Pw[(quad * 4 + r) * 136 + c * 16 + l16] = f2bf(s[c][r]);
        __builtin_amdgcn_s_setprio(1);
#pragma unroll
        for (int kc = 0; kc < 4; ++kc) {
            int kof = kc * 32 + quad * 8;
            bf16x8 ap = *(const bf16x8*)&Pw[l16 * 136 + kof];
#pragma unroll
            for (int j = 0; j < 4; ++j) {
                bf16x8 bv = *(const bf16x8*)&Vt[(j * 16 + l16) * 216 + kof];
                o[j] = __builtin_amdgcn_mfma_f32_16x16x32_bf16(ap, bv, o[j], 0, 0, 0);
            }
        }
        __builtin_amdgcn_s_setprio(0);
        // PV pass 2: P cols 128..207 -> buffer cols 0..79; cols 80..95 zeroed (p==0)
#pragma unroll
        for (int r = 0; r < 4; ++r)
            Pw[(quad * 4 + r) * 136 + 80 + l16] = 0;
#pragma unroll
        for (int c = 8; c < 13; ++c)
#pragma unroll
            for (int r = 0; r < 4; ++r)
                Pw[(quad * 4 + r) * 136 + (c - 8) * 16 + l16] = f2bf(s[c][r]);
        __builtin_amdgcn_s_setprio(1);
#pragma unroll
        for (int kc = 0; kc < 3; ++kc) {
            int kofA = kc * 32 + quad * 8;
            // kc==2, quad>=2 -> kt 208..223 where p==0 exactly; clamp LDS read in-range
            int kofB = (kc == 2 && quad >= 2) ? 0 : kofA;
            bf16x8 ap = *(const bf16x8*)&Pw[l16 * 136 + kofA];
#pragma unroll
            for (int j = 0; j < 4; ++j) {
                bf16x8 bv = *(const bf16x8*)&Vt[(j * 16 + l16) * 216 + 128 + kofB];
                o[j] = __builtin_amdgcn_mfma_f32_16x16x32_bf16(ap, bv, o[j], 0, 0, 0);
            }
        }
        __builtin_amdgcn_s_setprio(0);

        // epilogue: divide by l, store fp32 [B, tok, 768]
        int tokbase = tile * 16 + quad * 4;
#pragma unroll
        for (int r = 0; r < 4; ++r) {
            int tr = tokbase + r;
            if (tr >= 197) continue;
            float inv = 1.f / lsum[r];
#pragma unroll
            for (int j = 0; j < 4; ++j)
                out[((size_t)(bb * 197 + tr)) * 768 + h * 64 + j * 16 + l16] = o[j][r] * inv;
        }
    }
}

extern "C" void kernel_launch(void* const* d_in, const int* in_sizes, int n_in,
                              void* d_out, int out_size, void* d_ws, size_t ws_size,
                              hipStream_t stream) {
    const float* X    = (const float*)d_in[0];   // [64,197,768]
    const float* W    = (const float*)d_in[1];   // [768,2304]
    const float* bias = (const float*)d_in[2];   // [2304]
    float* out = (float*)d_out;                  // [64,197,768]

    // Xc and Wc (chunk-order staging images) live in d_ws
    unsigned short* Xc = (unsigned short*)d_ws;
    unsigned short* Wc = (unsigned short*)d_ws + XC_ELEMS;

    prep_kernel<<<7872, 256, 0, stream>>>(X, Xc, W, Wc);
    fused_kernel<<<768, 512, 0, stream>>>(Xc, Wc, bias, out);
}